// Round 16
// baseline (2533.567 us; speedup 1.0000x reference)
//
#include <hip/hip_runtime.h>
#include <hip/hip_bf16.h>

#define HDIM 4096
#define EDIM 64

typedef float f32x4 __attribute__((ext_vector_type(4)));

// Inputs: f32-backed bf16 (proven r13). Logit accumulation replicates
// numpy einsum's SSE sum-of-products bit-exactly:
//   4 lanes, lane[j] += a[h+j]*b[h+j]; lane[j] += a[h+4+j]*b[h+4+j]; h+=8
//   acc = (l0+l1)+(l2+l3);  then bf16-round (einsum bf16 output dtype).
__global__ __launch_bounds__(256) void router_probe(
    const float* __restrict__ hidden,
    const float* __restrict__ weight,
    float* __restrict__ out,
    int T)
{
    const int lane = threadIdx.x & 63;
    const int wave = threadIdx.x >> 6;
    const int t = blockIdx.x * 4 + wave;
    if (t >= T) return;

    const float* hrow = hidden + (size_t)t * HDIM;
    const float* wrow = weight + (size_t)lane * HDIM;

    float l0 = 0.f, l1 = 0.f, l2 = 0.f, l3 = 0.f;
    for (int h = 0; h < HDIM; h += 8) {
        f32x4 h0 = *reinterpret_cast<const f32x4*>(hrow + h);
        f32x4 h1 = *reinterpret_cast<const f32x4*>(hrow + h + 4);
        f32x4 w0 = *reinterpret_cast<const f32x4*>(wrow + h);
        f32x4 w1 = *reinterpret_cast<const f32x4*>(wrow + h + 4);
        l0 = __fadd_rn(l0, __fmul_rn(h0.x, w0.x));
        l1 = __fadd_rn(l1, __fmul_rn(h0.y, w0.y));
        l2 = __fadd_rn(l2, __fmul_rn(h0.z, w0.z));
        l3 = __fadd_rn(l3, __fmul_rn(h0.w, w0.w));
        l0 = __fadd_rn(l0, __fmul_rn(h1.x, w1.x));
        l1 = __fadd_rn(l1, __fmul_rn(h1.y, w1.y));
        l2 = __fadd_rn(l2, __fmul_rn(h1.z, w1.z));
        l3 = __fadd_rn(l3, __fmul_rn(h1.w, w1.w));
    }
    const float acc = __fadd_rn(__fadd_rn(l0, l1), __fadd_rn(l2, l3));

    // einsum(bf16,bf16) -> bf16 output, then astype(f32)
    const float lv = __bfloat162float(__float2bfloat16(acc));

    // wave softmax across 64 experts
    float mx = lv;
#pragma unroll
    for (int d = 1; d < 64; d <<= 1) mx = fmaxf(mx, __shfl_xor(mx, d));
    const float ev = expf(lv - mx);
    float s = ev;
#pragma unroll
    for (int d = 1; d < 64; d <<= 1) s += __shfl_xor(s, d);
    const float p = ev / s;

    // entropy = -sum p*log(p + 1e-9)
    float ent = p * logf(p + 1e-9f);
#pragma unroll
    for (int d = 1; d < 64; d <<= 1) ent += __shfl_xor(ent, d);
    const float Hent = -ent;

    // top-4: 4 rounds of stable wave-argmax (ties -> lowest expert id)
    float pv[4]; int pi[4];
    float cand = p;
#pragma unroll
    for (int r = 0; r < 4; ++r) {
        float bv = cand; int bi = lane;
#pragma unroll
        for (int d = 1; d < 64; d <<= 1) {
            float ov = __shfl_xor(bv, d);
            int   oi = __shfl_xor(bi, d);
            if (ov > bv || (ov == bv && oi < bi)) { bv = ov; bi = oi; }
        }
        pv[r] = bv; pi[r] = bi;
        if (lane == bi) cand = -1.f;
    }

    const int kk = (Hent < 0.3f) ? 1 : (Hent > 1.5f) ? 4 : 2;

    float wsum = 0.f;
#pragma unroll
    for (int r = 0; r < 4; ++r) if (r < kk) wsum += pv[r];

    if (lane == 0) {
        const size_t T4 = (size_t)T * 4;
        const size_t tt = (size_t)t;
#pragma unroll
        for (int r = 0; r < 4; ++r) {
            out[tt * 4 + r]      = (r < kk) ? (float)pi[r] : -1.f;
            out[T4 + tt * 4 + r] = (r < kk) ? pv[r] / wsum : 0.f;
        }
        out[2 * T4 + tt] = (float)kk;
    }
}

extern "C" void kernel_launch(void* const* d_in, const int* in_sizes, int n_in,
                              void* d_out, int out_size, void* d_ws, size_t ws_size,
                              hipStream_t stream) {
    const float* hidden = (const float*)d_in[0];
    const float* weight = (const float*)d_in[1];
    float* out = (float*)d_out;
    const int T = in_sizes[0] / HDIM;          // 16384
    const int blocks = (T + 3) / 4;            // 4 tokens (waves) per block
    hipLaunchKernelGGL(router_probe, dim3(blocks), dim3(256), 0, stream,
                       hidden, weight, out, T);
}

// Round 17
// 926.434 us; speedup vs baseline: 2.7348x; 2.7348x over previous
//
#include <hip/hip_runtime.h>
#include <hip/hip_bf16.h>

#define HDIM 4096
#define EDIM 64
#define ITOK 8   // tokens per thread: amortizes weight loads 8x

typedef float f32x4 __attribute__((ext_vector_type(4)));

// Semantics (locked, r16): inputs f32-backed bf16; logit = np-einsum-SSE
// 4-chain f32 accumulation (no FMA!), bf16-round, f32 routing, f32 out [idx|w|k].
// This round: wave = 64 experts (lane=e), each thread carries ITOK tokens
// so one weight f32x4 load feeds ITOK tokens' chains.
__global__ __launch_bounds__(256) void router_mt(
    const float* __restrict__ hidden,
    const float* __restrict__ weight,
    float* __restrict__ out,
    int T)
{
    const int lane = threadIdx.x & 63;
    const int wave = threadIdx.x >> 6;
    const int t0 = (blockIdx.x * 4 + wave) * ITOK;

    const float* wrow = weight + (size_t)lane * HDIM;

    float l[ITOK][4];
#pragma unroll
    for (int i = 0; i < ITOK; ++i) {
        l[i][0] = 0.f; l[i][1] = 0.f; l[i][2] = 0.f; l[i][3] = 0.f;
    }

    for (int h = 0; h < HDIM; h += 8) {
        const f32x4 w0 = *reinterpret_cast<const f32x4*>(wrow + h);
        const f32x4 w1 = *reinterpret_cast<const f32x4*>(wrow + h + 4);
#pragma unroll
        for (int i = 0; i < ITOK; ++i) {
            const float* hp = hidden + (size_t)(t0 + i) * HDIM + h;
            const f32x4 a0 = *reinterpret_cast<const f32x4*>(hp);
            const f32x4 a1 = *reinterpret_cast<const f32x4*>(hp + 4);
            // SSE chain order: slot c, then slot c+4 (bit-exact vs np gold)
            l[i][0] = __fadd_rn(l[i][0], __fmul_rn(a0.x, w0.x));
            l[i][1] = __fadd_rn(l[i][1], __fmul_rn(a0.y, w0.y));
            l[i][2] = __fadd_rn(l[i][2], __fmul_rn(a0.z, w0.z));
            l[i][3] = __fadd_rn(l[i][3], __fmul_rn(a0.w, w0.w));
            l[i][0] = __fadd_rn(l[i][0], __fmul_rn(a1.x, w1.x));
            l[i][1] = __fadd_rn(l[i][1], __fmul_rn(a1.y, w1.y));
            l[i][2] = __fadd_rn(l[i][2], __fmul_rn(a1.z, w1.z));
            l[i][3] = __fadd_rn(l[i][3], __fmul_rn(a1.w, w1.w));
        }
    }

    const size_t T4 = (size_t)T * 4;

#pragma unroll 1
    for (int i = 0; i < ITOK; ++i) {
        const float acc = __fadd_rn(__fadd_rn(l[i][0], l[i][1]),
                                    __fadd_rn(l[i][2], l[i][3]));
        const float lv = __bfloat162float(__float2bfloat16(acc));

        // wave softmax across 64 experts
        float mx = lv;
#pragma unroll
        for (int d = 1; d < 64; d <<= 1) mx = fmaxf(mx, __shfl_xor(mx, d));
        const float ev = expf(lv - mx);
        float s = ev;
#pragma unroll
        for (int d = 1; d < 64; d <<= 1) s += __shfl_xor(s, d);
        const float p = ev / s;

        // entropy = -sum p*log(p + 1e-9)
        float ent = p * logf(p + 1e-9f);
#pragma unroll
        for (int d = 1; d < 64; d <<= 1) ent += __shfl_xor(ent, d);
        const float Hent = -ent;

        // top-4: 4 rounds of stable wave-argmax (ties -> lowest expert id)
        float pv[4]; int pi[4];
        float cand = p;
#pragma unroll
        for (int r = 0; r < 4; ++r) {
            float bv = cand; int bi = lane;
#pragma unroll
            for (int d = 1; d < 64; d <<= 1) {
                float ov = __shfl_xor(bv, d);
                int   oi = __shfl_xor(bi, d);
                if (ov > bv || (ov == bv && oi < bi)) { bv = ov; bi = oi; }
            }
            pv[r] = bv; pi[r] = bi;
            if (lane == bi) cand = -1.f;
        }

        const int kk = (Hent < 0.3f) ? 1 : (Hent > 1.5f) ? 4 : 2;

        float wsum = 0.f;
#pragma unroll
        for (int r = 0; r < 4; ++r) if (r < kk) wsum += pv[r];

        if (lane == 0) {
            const size_t tt = (size_t)(t0 + i);
#pragma unroll
            for (int r = 0; r < 4; ++r) {
                out[tt * 4 + r]      = (r < kk) ? (float)pi[r] : -1.f;
                out[T4 + tt * 4 + r] = (r < kk) ? pv[r] / wsum : 0.f;
            }
            out[2 * T4 + tt] = (float)kk;
        }
    }
}

extern "C" void kernel_launch(void* const* d_in, const int* in_sizes, int n_in,
                              void* d_out, int out_size, void* d_ws, size_t ws_size,
                              hipStream_t stream) {
    const float* hidden = (const float*)d_in[0];
    const float* weight = (const float*)d_in[1];
    float* out = (float*)d_out;
    const int T = in_sizes[0] / HDIM;              // 16384
    const int blocks = T / (4 * ITOK);             // 512
    hipLaunchKernelGGL(router_mt, dim3(blocks), dim3(256), 0, stream,
                       hidden, weight, out, T);
}

// Round 18
// 184.261 us; speedup vs baseline: 13.7499x; 5.0278x over previous
//
#include <hip/hip_runtime.h>
#include <hip/hip_bf16.h>

#define HDIM 4096
#define EDIM 64
#define ITOK 4          // tokens per wave
#define BH   64         // h-chunk staged in LDS
#define NCH  (HDIM/BH)  // 64 chunks

typedef float f32x4 __attribute__((ext_vector_type(4)));

// Semantics (locked r16): inputs f32-backed bf16; logit = np-einsum-SSE
// 4-chain f32 mul/add (NO FMA), groups of 8 ascending h, (l0+l1)+(l2+l3),
// bf16-round, f32 routing, f32 out [idx 4T | w 4T | k T].
// Structure: lane=expert, wave=4 tokens. Weight chunk in LDS (dbuf),
// conflict-free stride-65 b32 reads; hidden wave-uniform loads.
__global__ __launch_bounds__(256) void router_lds(
    const float* __restrict__ hidden,
    const float* __restrict__ weight,
    float* __restrict__ out,
    int T)
{
    __shared__ float wlds[2][EDIM][BH + 1];   // 2 x 16.25 KB, stride 65

    const int tid  = threadIdx.x;
    const int lane = tid & 63;
    const int wv   = __builtin_amdgcn_readfirstlane(tid >> 6);  // uniform wave id
    const int t0   = (blockIdx.x * 4 + wv) * ITOK;

    // staging decomposition: thread -> (row, quarter)
    const int srow = tid >> 2;          // 0..63 expert row
    const int sq   = (tid & 3) * 16;    // 16-float segment within chunk

    float l[ITOK][4];
#pragma unroll
    for (int i = 0; i < ITOK; ++i)
        { l[i][0]=0.f; l[i][1]=0.f; l[i][2]=0.f; l[i][3]=0.f; }

    // ---- prologue: stage chunk 0 ----
    {
        const float* wp = weight + (size_t)srow * HDIM + sq;
#pragma unroll
        for (int j = 0; j < 16; j += 4) {
            f32x4 v = *reinterpret_cast<const f32x4*>(wp + j);
            wlds[0][srow][sq + j + 0] = v.x;
            wlds[0][srow][sq + j + 1] = v.y;
            wlds[0][srow][sq + j + 2] = v.z;
            wlds[0][srow][sq + j + 3] = v.w;
        }
    }
    __syncthreads();

    for (int c = 0; c < NCH; ++c) {
        const int cur = c & 1;
        // stage next chunk into other buffer (overlaps with compute)
        if (c + 1 < NCH) {
            const float* wp = weight + (size_t)srow * HDIM + (c + 1) * BH + sq;
#pragma unroll
            for (int j = 0; j < 16; j += 4) {
                f32x4 v = *reinterpret_cast<const f32x4*>(wp + j);
                wlds[cur ^ 1][srow][sq + j + 0] = v.x;
                wlds[cur ^ 1][srow][sq + j + 1] = v.y;
                wlds[cur ^ 1][srow][sq + j + 2] = v.z;
                wlds[cur ^ 1][srow][sq + j + 3] = v.w;
            }
        }

        const int h0 = c * BH;
#pragma unroll
        for (int g = 0; g < BH / 8; ++g) {
            // weight group for this lane's expert (conflict-free b32 reads)
            float w0x = wlds[cur][lane][g*8+0], w0y = wlds[cur][lane][g*8+1];
            float w0z = wlds[cur][lane][g*8+2], w0w = wlds[cur][lane][g*8+3];
            float w1x = wlds[cur][lane][g*8+4], w1y = wlds[cur][lane][g*8+5];
            float w1z = wlds[cur][lane][g*8+6], w1w = wlds[cur][lane][g*8+7];
#pragma unroll
            for (int i = 0; i < ITOK; ++i) {
                const float* hp = hidden + (size_t)(t0 + i) * HDIM + h0 + g*8;
                const f32x4 a0 = *reinterpret_cast<const f32x4*>(hp);
                const f32x4 a1 = *reinterpret_cast<const f32x4*>(hp + 4);
                l[i][0] = __fadd_rn(l[i][0], __fmul_rn(a0.x, w0x));
                l[i][1] = __fadd_rn(l[i][1], __fmul_rn(a0.y, w0y));
                l[i][2] = __fadd_rn(l[i][2], __fmul_rn(a0.z, w0z));
                l[i][3] = __fadd_rn(l[i][3], __fmul_rn(a0.w, w0w));
                l[i][0] = __fadd_rn(l[i][0], __fmul_rn(a1.x, w1x));
                l[i][1] = __fadd_rn(l[i][1], __fmul_rn(a1.y, w1y));
                l[i][2] = __fadd_rn(l[i][2], __fmul_rn(a1.z, w1z));
                l[i][3] = __fadd_rn(l[i][3], __fmul_rn(a1.w, w1w));
            }
        }
        __syncthreads();
    }

    const size_t T4 = (size_t)T * 4;

#pragma unroll 1
    for (int i = 0; i < ITOK; ++i) {
        const float acc = __fadd_rn(__fadd_rn(l[i][0], l[i][1]),
                                    __fadd_rn(l[i][2], l[i][3]));
        const float lv = __bfloat162float(__float2bfloat16(acc));

        float mx = lv;
#pragma unroll
        for (int d = 1; d < 64; d <<= 1) mx = fmaxf(mx, __shfl_xor(mx, d));
        const float ev = expf(lv - mx);
        float s = ev;
#pragma unroll
        for (int d = 1; d < 64; d <<= 1) s += __shfl_xor(s, d);
        const float p = ev / s;

        float ent = p * logf(p + 1e-9f);
#pragma unroll
        for (int d = 1; d < 64; d <<= 1) ent += __shfl_xor(ent, d);
        const float Hent = -ent;

        float pv[4]; int pi[4];
        float cand = p;
#pragma unroll
        for (int r = 0; r < 4; ++r) {
            float bv = cand; int bi = lane;
#pragma unroll
            for (int d = 1; d < 64; d <<= 1) {
                float ov = __shfl_xor(bv, d);
                int   oi = __shfl_xor(bi, d);
                if (ov > bv || (ov == bv && oi < bi)) { bv = ov; bi = oi; }
            }
            pv[r] = bv; pi[r] = bi;
            if (lane == bi) cand = -1.f;
        }

        const int kk = (Hent < 0.3f) ? 1 : (Hent > 1.5f) ? 4 : 2;

        float wsum = 0.f;
#pragma unroll
        for (int r = 0; r < 4; ++r) if (r < kk) wsum += pv[r];

        if (lane == 0) {
            const size_t tt = (size_t)(t0 + i);
#pragma unroll
            for (int r = 0; r < 4; ++r) {
                out[tt * 4 + r]      = (r < kk) ? (float)pi[r] : -1.f;
                out[T4 + tt * 4 + r] = (r < kk) ? pv[r] / wsum : 0.f;
            }
            out[2 * T4 + tt] = (float)kk;
        }
    }
}

extern "C" void kernel_launch(void* const* d_in, const int* in_sizes, int n_in,
                              void* d_out, int out_size, void* d_ws, size_t ws_size,
                              hipStream_t stream) {
    const float* hidden = (const float*)d_in[0];
    const float* weight = (const float*)d_in[1];
    float* out = (float*)d_out;
    const int T = in_sizes[0] / HDIM;              // 16384
    const int blocks = T / (4 * ITOK);             // 1024
    hipLaunchKernelGGL(router_lds, dim3(blocks), dim3(256), 0, stream,
                       hidden, weight, out, T);
}

// Round 19
// 183.474 us; speedup vs baseline: 13.8089x; 1.0043x over previous
//
#include <hip/hip_runtime.h>
#include <hip/hip_bf16.h>

#define HDIM 4096
#define EDIM 64
#define ITOK 4          // tokens per wave
#define NW   8          // waves per block (512 threads)
#define BH   64         // h-chunk staged in LDS
#define NCH  (HDIM/BH)  // 64 chunks

typedef float f32x4 __attribute__((ext_vector_type(4)));

// Semantics (locked r16): inputs f32-backed bf16; logit = np-einsum-SSE
// 4-chain f32 mul/add (NO FMA), groups of 8 ascending h, (l0+l1)+(l2+l3),
// bf16-round, f32 routing, f32 out [idx 4T | w 4T | k T].
// r18: 512-thread blocks -> 32 waves/CU (occupancy 2x), conflict-free staging.
__global__ __launch_bounds__(512) void router_lds(
    const float* __restrict__ hidden,
    const float* __restrict__ weight,
    float* __restrict__ out,
    int T)
{
    __shared__ float wlds[2][EDIM][BH + 1];   // 2 x 16.25 KB, stride 65

    const int tid  = threadIdx.x;
    const int lane = tid & 63;
    const int wv   = __builtin_amdgcn_readfirstlane(tid >> 6);  // uniform wave id
    const int t0   = (blockIdx.x * NW + wv) * ITOK;

    // staging decomposition: 512 threads, 8 floats each per chunk.
    // srow=tid>>3 (expert row), sq=(tid&7)*8. Writes hit banks
    // (srow + 8q + j) mod 32 -> all 64 lanes distinct mod 32 pairs: conflict-free.
    const int srow = tid >> 3;
    const int sq   = (tid & 7) * 8;

    float l[ITOK][4];
#pragma unroll
    for (int i = 0; i < ITOK; ++i)
        { l[i][0]=0.f; l[i][1]=0.f; l[i][2]=0.f; l[i][3]=0.f; }

    // ---- prologue: stage chunk 0 ----
    {
        const float* wp = weight + (size_t)srow * HDIM + sq;
        f32x4 v0 = *reinterpret_cast<const f32x4*>(wp);
        f32x4 v1 = *reinterpret_cast<const f32x4*>(wp + 4);
        wlds[0][srow][sq + 0] = v0.x; wlds[0][srow][sq + 1] = v0.y;
        wlds[0][srow][sq + 2] = v0.z; wlds[0][srow][sq + 3] = v0.w;
        wlds[0][srow][sq + 4] = v1.x; wlds[0][srow][sq + 5] = v1.y;
        wlds[0][srow][sq + 6] = v1.z; wlds[0][srow][sq + 7] = v1.w;
    }
    __syncthreads();

    for (int c = 0; c < NCH; ++c) {
        const int cur = c & 1;
        if (c + 1 < NCH) {
            const float* wp = weight + (size_t)srow * HDIM + (c + 1) * BH + sq;
            f32x4 v0 = *reinterpret_cast<const f32x4*>(wp);
            f32x4 v1 = *reinterpret_cast<const f32x4*>(wp + 4);
            wlds[cur ^ 1][srow][sq + 0] = v0.x; wlds[cur ^ 1][srow][sq + 1] = v0.y;
            wlds[cur ^ 1][srow][sq + 2] = v0.z; wlds[cur ^ 1][srow][sq + 3] = v0.w;
            wlds[cur ^ 1][srow][sq + 4] = v1.x; wlds[cur ^ 1][srow][sq + 5] = v1.y;
            wlds[cur ^ 1][srow][sq + 6] = v1.z; wlds[cur ^ 1][srow][sq + 7] = v1.w;
        }

        const int h0 = c * BH;
#pragma unroll
        for (int g = 0; g < BH / 8; ++g) {
            float w0x = wlds[cur][lane][g*8+0], w0y = wlds[cur][lane][g*8+1];
            float w0z = wlds[cur][lane][g*8+2], w0w = wlds[cur][lane][g*8+3];
            float w1x = wlds[cur][lane][g*8+4], w1y = wlds[cur][lane][g*8+5];
            float w1z = wlds[cur][lane][g*8+6], w1w = wlds[cur][lane][g*8+7];
#pragma unroll
            for (int i = 0; i < ITOK; ++i) {
                const float* hp = hidden + (size_t)(t0 + i) * HDIM + h0 + g*8;
                const f32x4 a0 = *reinterpret_cast<const f32x4*>(hp);
                const f32x4 a1 = *reinterpret_cast<const f32x4*>(hp + 4);
                l[i][0] = __fadd_rn(l[i][0], __fmul_rn(a0.x, w0x));
                l[i][1] = __fadd_rn(l[i][1], __fmul_rn(a0.y, w0y));
                l[i][2] = __fadd_rn(l[i][2], __fmul_rn(a0.z, w0z));
                l[i][3] = __fadd_rn(l[i][3], __fmul_rn(a0.w, w0w));
                l[i][0] = __fadd_rn(l[i][0], __fmul_rn(a1.x, w1x));
                l[i][1] = __fadd_rn(l[i][1], __fmul_rn(a1.y, w1y));
                l[i][2] = __fadd_rn(l[i][2], __fmul_rn(a1.z, w1z));
                l[i][3] = __fadd_rn(l[i][3], __fmul_rn(a1.w, w1w));
            }
        }
        __syncthreads();
    }

    const size_t T4 = (size_t)T * 4;

#pragma unroll 1
    for (int i = 0; i < ITOK; ++i) {
        const float acc = __fadd_rn(__fadd_rn(l[i][0], l[i][1]),
                                    __fadd_rn(l[i][2], l[i][3]));
        const float lv = __bfloat162float(__float2bfloat16(acc));

        float mx = lv;
#pragma unroll
        for (int d = 1; d < 64; d <<= 1) mx = fmaxf(mx, __shfl_xor(mx, d));
        const float ev = expf(lv - mx);
        float s = ev;
#pragma unroll
        for (int d = 1; d < 64; d <<= 1) s += __shfl_xor(s, d);
        const float p = ev / s;

        float ent = p * logf(p + 1e-9f);
#pragma unroll
        for (int d = 1; d < 64; d <<= 1) ent += __shfl_xor(ent, d);
        const float Hent = -ent;

        float pv[4]; int pi[4];
        float cand = p;
#pragma unroll
        for (int r = 0; r < 4; ++r) {
            float bv = cand; int bi = lane;
#pragma unroll
            for (int d = 1; d < 64; d <<= 1) {
                float ov = __shfl_xor(bv, d);
                int   oi = __shfl_xor(bi, d);
                if (ov > bv || (ov == bv && oi < bi)) { bv = ov; bi = oi; }
            }
            pv[r] = bv; pi[r] = bi;
            if (lane == bi) cand = -1.f;
        }

        const int kk = (Hent < 0.3f) ? 1 : (Hent > 1.5f) ? 4 : 2;

        float wsum = 0.f;
#pragma unroll
        for (int r = 0; r < 4; ++r) if (r < kk) wsum += pv[r];

        if (lane == 0) {
            const size_t tt = (size_t)(t0 + i);
#pragma unroll
            for (int r = 0; r < 4; ++r) {
                out[tt * 4 + r]      = (r < kk) ? (float)pi[r] : -1.f;
                out[T4 + tt * 4 + r] = (r < kk) ? pv[r] / wsum : 0.f;
            }
            out[2 * T4 + tt] = (float)kk;
        }
    }
}

extern "C" void kernel_launch(void* const* d_in, const int* in_sizes, int n_in,
                              void* d_out, int out_size, void* d_ws, size_t ws_size,
                              hipStream_t stream) {
    const float* hidden = (const float*)d_in[0];
    const float* weight = (const float*)d_in[1];
    float* out = (float*)d_out;
    const int T = in_sizes[0] / HDIM;              // 16384
    const int blocks = T / (NW * ITOK);            // 512
    hipLaunchKernelGGL(router_lds, dim3(blocks), dim3(512), 0, stream,
                       hidden, weight, out, T);
}